// Round 1
// 340.030 us; speedup vs baseline: 1.1826x; 1.1826x over previous
//
#include <hip/hip_runtime.h>
#include <stdint.h>

#define P 2048
#define R 65536
#define DD 512
#define BM 256
#define BN 256
#define BK 64
#define NT (DD / BK)   // 8 K-tiles

typedef __attribute__((ext_vector_type(8))) short short8;
typedef __attribute__((ext_vector_type(4))) float f32x4;

__device__ inline unsigned short f2bf(float f) {
  unsigned int u = __float_as_uint(f);
  u += 0x7fffu + ((u >> 16) & 1u);   // round-to-nearest-even
  return (unsigned short)(u >> 16);
}

__device__ inline void gload_lds16(const void* g, void* l) {
  __builtin_amdgcn_global_load_lds(
      (const __attribute__((address_space(1))) unsigned int*)g,
      (__attribute__((address_space(3))) unsigned int*)l,
      16, 0, 0);
}

// ---- kernel 1: fp32 -> bf16 conversion + fp32 row norms; one wave per row ----
__global__ __launch_bounds__(256) void k_convert(
    const float* __restrict__ pred, const float* __restrict__ cand,
    unsigned short* __restrict__ Abf, unsigned short* __restrict__ Bbf,
    float* __restrict__ nx, float* __restrict__ ny,
    unsigned int* __restrict__ minp)
{
  if (blockIdx.x == 0 && threadIdx.x == 0) *minp = 0x7f800000u; // +inf bits
  int gw   = (blockIdx.x * 256 + threadIdx.x) >> 6;  // global wave = row
  int lane = threadIdx.x & 63;
  if (gw >= P + R) return;
  const float* src; unsigned short* dst; float* np;
  if (gw < P) { src = pred + (size_t)gw * DD; dst = Abf + (size_t)gw * DD; np = nx + gw; }
  else { int r = gw - P; src = cand + (size_t)r * DD; dst = Bbf + (size_t)r * DD; np = ny + r; }
  const float4* s4 = ((const float4*)src) + lane * 2;
  float4 v0 = s4[0], v1 = s4[1];
  float ss = v0.x*v0.x + v0.y*v0.y + v0.z*v0.z + v0.w*v0.w
           + v1.x*v1.x + v1.y*v1.y + v1.z*v1.z + v1.w*v1.w;
  union { unsigned short h[8]; uint4 v; } pk;
  pk.h[0]=f2bf(v0.x); pk.h[1]=f2bf(v0.y); pk.h[2]=f2bf(v0.z); pk.h[3]=f2bf(v0.w);
  pk.h[4]=f2bf(v1.x); pk.h[5]=f2bf(v1.y); pk.h[6]=f2bf(v1.z); pk.h[7]=f2bf(v1.w);
  *(uint4*)(dst + (size_t)lane * 8) = pk.v;
  #pragma unroll
  for (int off = 32; off; off >>= 1) ss += __shfl_down(ss, off, 64);
  if (lane == 0) *np = ss;
}

// ---- kernel 2: 256x256 bf16 MFMA tile GEMM (A·B^T), BK=64, 8 waves (2Mx4N),
//      double-buffered LDS, counted-vmcnt pipeline (T3/T4), setprio (T5),
//      XCD-aware block swizzle (T1), chunk-XOR LDS swizzle (T2, conflict-free),
//      fused min epilogue.
// LDS layout per operand/buffer: row-major [256][64] bf16; the 8 16B-chunks of
// each row stored permuted: stored_chunk = data_chunk ^ (row & 7). Permutation
// applied on the GLOBAL source address per lane (global_load_lds writes LDS at
// wave-uniform base + lane*16 — linear dest, inverse-swizzled source; rule #21).
// Pipeline: prologue stages tiles 0,1. Iteration kt computes from buf kt&1
// (2 phases x 32 MFMA, B-frags hoisted so each LDS element is read once per
// consuming wave), then: raw s_barrier -> stage tile kt+2 into freed buffer ->
// s_waitcnt vmcnt(8) (tile kt+1 landed; kt+2's 8 loads stay in flight across
// the whole next iteration) -> raw s_barrier. Raw barriers (not __syncthreads)
// so the compiler cannot insert the vmcnt(0) drain that caps the m97 structure.
__global__ __launch_bounds__(512, 2) void k_gemm_min(
    const unsigned short* __restrict__ Abf, const unsigned short* __restrict__ Bbf,
    const float* __restrict__ nx, const float* __restrict__ ny,
    unsigned int* __restrict__ minp)
{
  __shared__ __align__(16) unsigned short As[2][BM * BK];   // 2 x 32 KB
  __shared__ __align__(16) unsigned short Bs[2][BN * BK];   // 2 x 32 KB
  __shared__ float wmin[8];

  const int tid  = threadIdx.x;
  const int wave = tid >> 6;          // 0..7
  const int lane = tid & 63;

  // XCD-aware bijective remap: 2048 blocks, 8 XCDs, 256 contiguous per XCD.
  const int raw = blockIdx.x;
  const int wg  = (raw & 7) * 256 + (raw >> 3);
  const int by  = wg & 7;             // pred tile fast -> 8 adjacent wg share cand tile
  const int bx  = wg >> 3;            // cand tile
  const int rowA0 = by * BM, rowB0 = bx * BN;
  const int wr = wave >> 2;           // 0..1 : M half   (wave tile 128x64)
  const int wc = wave & 3;            // 0..3 : N quarter

  f32x4 zero = {0.f, 0.f, 0.f, 0.f};
  f32x4 acc[8][4];
  #pragma unroll
  for (int i = 0; i < 8; ++i)
    #pragma unroll
    for (int j = 0; j < 4; ++j) acc[i][j] = zero;

  // staging: per operand per K-tile 32 wave-instrs (8 waves x t=0..3), each
  // covering 8 rows x 64 cols. lane L -> local row L>>3, stored chunk L&7,
  // sourcing global data chunk (L&7)^(L>>3).
  const int rloc = lane >> 3;            // 0..7
  const int cswz = (lane & 7) ^ rloc;    // swizzled source chunk
  const unsigned short* gA[4]; const unsigned short* gB[4];
  int lOff[4];
  #pragma unroll
  for (int t = 0; t < 4; ++t) {
    const int ii = wave * 4 + t;          // 0..31
    const int rr = ii * 8 + rloc;         // tile row 0..255
    gA[t] = Abf + (size_t)(rowA0 + rr) * DD + cswz * 8;
    gB[t] = Bbf + (size_t)(rowB0 + rr) * DD + cswz * 8;
    lOff[t] = ii * 512;                   // 1 KB per wave-instr
  }

#define STAGE(c, kt) do { const int _k0 = (kt) * BK;            \
    _Pragma("unroll")                                           \
    for (int _t = 0; _t < 4; ++_t) {                            \
      gload_lds16(gA[_t] + _k0, &As[(c)][lOff[_t]]);            \
      gload_lds16(gB[_t] + _k0, &Bs[(c)][lOff[_t]]);            \
    } } while (0)

  // fragment read geometry. A frag i: row wr*128 + i*16 + m; B frag j: row
  // wc*64 + j*16 + m; k-chunk (h*4+quad) stored at chunk ^ (m&7).
  const int m = lane & 15, quad = lane >> 4, mb = m & 7;
  const int aRow0 = (wr * 128 + m) * BK;
  const int bRow0 = (wc * 64  + m) * BK;
  const int swz0 = ((quad    ) ^ mb) * 8;
  const int swz1 = ((quad + 4) ^ mb) * 8;

  STAGE(0, 0);
  STAGE(1, 1);
  asm volatile("s_waitcnt vmcnt(8)" ::: "memory");   // tile 0 landed
  __builtin_amdgcn_s_barrier();

  for (int kt = 0; kt < NT; ++kt) {
    const int c = kt & 1;
    const unsigned short* A0 = &As[c][0];
    const unsigned short* B0 = &Bs[c][0];

    // B fragments hoisted: read once per K-tile (8 ds_read_b128, 32 VGPRs)
    short8 bfr[4][2];
    #pragma unroll
    for (int j = 0; j < 4; ++j) {
      const unsigned short* bp = B0 + bRow0 + j * 16 * BK;
      bfr[j][0] = *(const short8*)(bp + swz0);
      bfr[j][1] = *(const short8*)(bp + swz1);
    }
    #pragma unroll
    for (int mh = 0; mh < 2; ++mh) {
      short8 af[4][2];
      #pragma unroll
      for (int i = 0; i < 4; ++i) {
        const unsigned short* ap = A0 + aRow0 + (mh * 4 + i) * 16 * BK;
        af[i][0] = *(const short8*)(ap + swz0);
        af[i][1] = *(const short8*)(ap + swz1);
      }
      __builtin_amdgcn_s_setprio(1);
      #pragma unroll
      for (int i = 0; i < 4; ++i)
        #pragma unroll
        for (int j = 0; j < 4; ++j) {
          acc[mh*4+i][j] = __builtin_amdgcn_mfma_f32_16x16x32_bf16(af[i][0], bfr[j][0], acc[mh*4+i][j], 0, 0, 0);
          acc[mh*4+i][j] = __builtin_amdgcn_mfma_f32_16x16x32_bf16(af[i][1], bfr[j][1], acc[mh*4+i][j], 0, 0, 0);
        }
      __builtin_amdgcn_s_setprio(0);
      asm volatile("" ::: "memory");   // phase fence: no cross-phase ds_read motion
    }

    if (kt < NT - 1) {
      __builtin_amdgcn_s_barrier();    // all waves done reading buf c
      if (kt + 2 < NT) {
        STAGE(c, kt + 2);              // 8 loads fly across the next iteration
        asm volatile("s_waitcnt vmcnt(8)" ::: "memory");  // tile kt+1 landed
      } else {
        asm volatile("s_waitcnt vmcnt(0)" ::: "memory");  // drain last tile
      }
      __builtin_amdgcn_s_barrier();    // buf c^1 ready for everyone
    }
  }
#undef STAGE

  // epilogue: d^2 = ||x||^2 + ||y||^2 - 2*dot ; C/D layout col=lane&15, row=quad*4+reg
  float lmin = 3.4e38f;
  #pragma unroll
  for (int i = 0; i < 8; ++i) {
    const int mbase = rowA0 + wr * 128 + i * 16 + quad * 4;
    float4 nxv = *(const float4*)(nx + mbase);
    #pragma unroll
    for (int j = 0; j < 4; ++j) {
      const int n = rowB0 + wc * 64 + j * 16 + m;
      const float nyv = ny[n];
      f32x4 a = acc[i][j];
      lmin = fminf(lmin, nxv.x + nyv - 2.0f * a[0]);
      lmin = fminf(lmin, nxv.y + nyv - 2.0f * a[1]);
      lmin = fminf(lmin, nxv.z + nyv - 2.0f * a[2]);
      lmin = fminf(lmin, nxv.w + nyv - 2.0f * a[3]);
    }
  }
  #pragma unroll
  for (int off = 32; off; off >>= 1) lmin = fminf(lmin, __shfl_down(lmin, off, 64));
  if (lane == 0) wmin[wave] = lmin;
  __syncthreads();
  if (tid == 0) {
    float mn = wmin[0];
    #pragma unroll
    for (int w = 1; w < 8; ++w) mn = fminf(mn, wmin[w]);
    atomicMin(minp, __float_as_uint(fmaxf(mn, 0.0f)));
  }
}

// ---- fallback (only if ws too small): exact fp32 brute force ----
__global__ __launch_bounds__(64) void k_initmin(unsigned int* minp) {
  if (threadIdx.x == 0) *minp = 0x7f800000u;
}

__global__ __launch_bounds__(256) void k_brute(
    const float* __restrict__ pred, const float* __restrict__ cand,
    unsigned int* __restrict__ minp)
{
  __shared__ float yrow[DD];
  __shared__ float wm[4];
  const int c = blockIdx.x;
  for (int i = threadIdx.x; i < DD; i += 256) yrow[i] = cand[(size_t)c * DD + i];
  __syncthreads();
  float lmin = 3.4e38f;
  for (int p = threadIdx.x; p < P; p += 256) {
    const float* xp = pred + (size_t)p * DD;
    float s = 0.f;
    for (int k = 0; k < DD; ++k) { float d = xp[k] - yrow[k]; s = fmaf(d, d, s); }
    lmin = fminf(lmin, s);
  }
  #pragma unroll
  for (int off = 32; off; off >>= 1) lmin = fminf(lmin, __shfl_down(lmin, off, 64));
  if ((threadIdx.x & 63) == 0) wm[threadIdx.x >> 6] = lmin;
  __syncthreads();
  if (threadIdx.x == 0) {
    float mn = fminf(fminf(wm[0], wm[1]), fminf(wm[2], wm[3]));
    atomicMin(minp, __float_as_uint(fmaxf(mn, 0.0f)));
  }
}

__global__ __launch_bounds__(64) void k_finalize(const unsigned int* minp, float* out) {
  if (threadIdx.x == 0) out[0] = sqrtf(__uint_as_float(*minp));
}

extern "C" void kernel_launch(void* const* d_in, const int* in_sizes, int n_in,
                              void* d_out, int out_size, void* d_ws, size_t ws_size,
                              hipStream_t stream) {
  const float* pred = (const float*)d_in[0];
  const float* cand = (const float*)d_in[1];
  float* out = (float*)d_out;

  // ws layout: [0] min-bits | +16 floats: nx[2048] | ny[65536] | Abf bf16[2048*512] | Bbf bf16[65536*512]
  unsigned int* minp = (unsigned int*)d_ws;
  float* wsf = (float*)d_ws;
  float* nx = wsf + 16;
  float* ny = nx + P;
  unsigned short* Abf = (unsigned short*)(ny + R);
  unsigned short* Bbf = Abf + (size_t)P * DD;
  const size_t need = (size_t)(16 + P + R) * 4 + ((size_t)P * DD + (size_t)R * DD) * 2;

  if (ws_size >= need) {
    const int rows = P + R;                 // 67584 rows, 4 waves/block
    k_convert<<<rows / 4, 256, 0, stream>>>(pred, cand, Abf, Bbf, nx, ny, minp);
    k_gemm_min<<<(P / BM) * (R / BN), 512, 0, stream>>>(Abf, Bbf, nx, ny, minp);
  } else {
    k_initmin<<<1, 64, 0, stream>>>(minp);
    k_brute<<<R, 256, 0, stream>>>(pred, cand, minp);
  }
  k_finalize<<<1, 64, 0, stream>>>(minp, out);
}

// Round 2
// 336.283 us; speedup vs baseline: 1.1958x; 1.0111x over previous
//
#include <hip/hip_runtime.h>
#include <stdint.h>

#define P 2048
#define R 65536
#define DD 512
#define BM 256
#define BN 256
#define BK 64
#define NT (DD / BK)   // 8 K-tiles

typedef __attribute__((ext_vector_type(8))) short short8;
typedef __attribute__((ext_vector_type(4))) float f32x4;

__device__ inline unsigned short f2bf(float f) {
  unsigned int u = __float_as_uint(f);
  u += 0x7fffu + ((u >> 16) & 1u);   // round-to-nearest-even
  return (unsigned short)(u >> 16);
}

__device__ inline void gload_lds16(const void* g, void* l) {
  __builtin_amdgcn_global_load_lds(
      (const __attribute__((address_space(1))) unsigned int*)g,
      (__attribute__((address_space(3))) unsigned int*)l,
      16, 0, 0);
}

// ---- kernel 1: fp32 -> bf16 conversion + fp32 row norms; one wave per row ----
__global__ __launch_bounds__(256) void k_convert(
    const float* __restrict__ pred, const float* __restrict__ cand,
    unsigned short* __restrict__ Abf, unsigned short* __restrict__ Bbf,
    float* __restrict__ nx, float* __restrict__ ny,
    unsigned int* __restrict__ minp)
{
  if (blockIdx.x == 0 && threadIdx.x == 0) *minp = 0x7f800000u; // +inf bits
  int gw   = (blockIdx.x * 256 + threadIdx.x) >> 6;  // global wave = row
  int lane = threadIdx.x & 63;
  if (gw >= P + R) return;
  const float* src; unsigned short* dst; float* np;
  if (gw < P) { src = pred + (size_t)gw * DD; dst = Abf + (size_t)gw * DD; np = nx + gw; }
  else { int r = gw - P; src = cand + (size_t)r * DD; dst = Bbf + (size_t)r * DD; np = ny + r; }
  const float4* s4 = ((const float4*)src) + lane * 2;
  float4 v0 = s4[0], v1 = s4[1];
  float ss = v0.x*v0.x + v0.y*v0.y + v0.z*v0.z + v0.w*v0.w
           + v1.x*v1.x + v1.y*v1.y + v1.z*v1.z + v1.w*v1.w;
  union { unsigned short h[8]; uint4 v; } pk;
  pk.h[0]=f2bf(v0.x); pk.h[1]=f2bf(v0.y); pk.h[2]=f2bf(v0.z); pk.h[3]=f2bf(v0.w);
  pk.h[4]=f2bf(v1.x); pk.h[5]=f2bf(v1.y); pk.h[6]=f2bf(v1.z); pk.h[7]=f2bf(v1.w);
  *(uint4*)(dst + (size_t)lane * 8) = pk.v;
  #pragma unroll
  for (int off = 32; off; off >>= 1) ss += __shfl_down(ss, off, 64);
  if (lane == 0) *np = ss;
}

// ---- kernel 2: 256x256 bf16 MFMA GEMM (A·B^T), BK=64, 8 waves (2Mx4N),
//      double-buffered LDS, 4-phase-per-tile schedule (m201 port: T3+T4),
//      half-tile-granular staging with single counted vmcnt(6) per tile,
//      setprio around MFMA clusters (T5), XCD swizzle (T1), chunk-XOR LDS
//      swizzle (T2, measured conflict-free), fused min epilogue.
//
// LDS: per operand/buffer row-major [256][64] bf16; 16B-chunks of each row
// stored permuted: stored_chunk = data_chunk ^ (row & 7), applied via the
// GLOBAL source address (linear gload_lds dest + inverse-swizzled source).
//
// Staging halves (16 KB each = 2 gload_lds/wave, 8-row groups):
//   A-ih0 = rows {0-63, 128-191}   (read only in phase 0: frag regs persist)
//   B-jh0 = rows {r: (r>>5)&1==0}  (read only in phase 0)
//   B-jh1 = rows {r: (r>>5)&1==1}  (read only in phase 1)
//   A-ih1 = rows {64-127, 192-255} (read only in phase 2)
// Stage schedule (tile T, phases p=0..3):
//   p0: A-ih1(T+1) -> slot^1   (that region last read at tile T-1 p2)
//   p1: A-ih0(T+2) -> slot     (freed after this tile's p0)
//   p2: B-jh0(T+2) -> slot     (freed after p0)
//   p3: B-jh1(T+2) -> slot     (freed after p1)
// Per-tile halves are issued in order [A-ih0, B-jh0, B-jh1, A-ih1], so at
// tile entry vmcnt(6) (3 newest halves in flight) proves all 4 halves of
// this tile landed. vmcnt never drains to 0 until the final tile.
__global__ __launch_bounds__(512, 2) void k_gemm_min(
    const unsigned short* __restrict__ Abf, const unsigned short* __restrict__ Bbf,
    const float* __restrict__ nx, const float* __restrict__ ny,
    unsigned int* __restrict__ minp)
{
  __shared__ __align__(16) unsigned short As[2][BM * BK];   // 2 x 32 KB
  __shared__ __align__(16) unsigned short Bs[2][BN * BK];   // 2 x 32 KB
  __shared__ float wmin[8];

  const int tid  = threadIdx.x;
  const int wave = tid >> 6;          // 0..7
  const int lane = tid & 63;

  // XCD-aware bijective remap: 2048 blocks, 8 XCDs, 256 contiguous per XCD.
  const int raw = blockIdx.x;
  const int wg  = (raw & 7) * 256 + (raw >> 3);
  const int by  = wg & 7;             // pred tile fast -> 8 adjacent wg share cand tile
  const int bx  = wg >> 3;            // cand tile
  const int rowA0 = by * BM, rowB0 = bx * BN;
  const int wr = wave >> 2;           // 0..1 : M half   (wave tile 128x64)
  const int wc = wave & 3;            // 0..3 : N quarter

  f32x4 zero = {0.f, 0.f, 0.f, 0.f};
  f32x4 acc[8][4];
  #pragma unroll
  for (int i = 0; i < 8; ++i)
    #pragma unroll
    for (int j = 0; j < 4; ++j) acc[i][j] = zero;

  // ---- staging descriptors: per wave, 2 groups (8 rows x 64 cols = 1 KB)
  // per half. lane L -> local row L>>3, stored chunk L&7, source data chunk
  // (L&7)^(L>>3) (row&7 == L>>3 since groups are 8-row aligned).
  const int rloc = lane >> 3;
  const int cswz = (lane & 7) ^ rloc;
  const unsigned short* aBase = Abf + (size_t)(rowA0 + rloc) * DD + cswz * 8;
  const unsigned short* bBase = Bbf + (size_t)(rowB0 + rloc) * DD + cswz * 8;
  const int ldsLane = lane * 8;       // shorts
  int gA[2][2], gB[2][2];             // [half][t] group ids (wave-uniform)
  #pragma unroll
  for (int t = 0; t < 2; ++t) {
    const int idx = wave * 2 + t;     // 0..15
    #pragma unroll
    for (int h = 0; h < 2; ++h) {
      gA[h][t] = ((idx >> 3) << 4) | (h << 3) | (idx & 7);
      gB[h][t] = ((idx >> 2) << 3) | (h << 2) | (idx & 3);
    }
  }

#define STAGE_A(h, s, tt) do { _Pragma("unroll")                              \
    for (int _t = 0; _t < 2; ++_t) { const int _g = gA[h][_t];                \
      gload_lds16(aBase + (size_t)_g * (8 * DD) + (tt) * BK,                  \
                  &As[s][_g * 512 + ldsLane]); } } while (0)
#define STAGE_B(h, s, tt) do { _Pragma("unroll")                              \
    for (int _t = 0; _t < 2; ++_t) { const int _g = gB[h][_t];                \
      gload_lds16(bBase + (size_t)_g * (8 * DD) + (tt) * BK,                  \
                  &Bs[s][_g * 512 + ldsLane]); } } while (0)

  // fragment read geometry (swizzled chunk offsets unchanged)
  const int m = lane & 15, quad = lane >> 4, mb = m & 7;
  const int aRow0 = (wr * 128 + m) * BK;
  const int bRow0 = (wc * 64  + m) * BK;
  const int swz0 = ((quad    ) ^ mb) * 8;
  const int swz1 = ((quad + 4) ^ mb) * 8;

  // ---- prologue: tile0 fully + tile1's first 3 halves (tile1's A-ih1 is
  // staged at tile0 p0). Issue order matches steady-state per-tile order.
  STAGE_A(0, 0, 0); STAGE_B(0, 0, 0); STAGE_B(1, 0, 0); STAGE_A(1, 0, 0);
  STAGE_A(0, 1, 1); STAGE_B(0, 1, 1); STAGE_B(1, 1, 1);
  asm volatile("s_waitcnt vmcnt(6)" ::: "memory");   // tile 0's 8 loads landed
  __builtin_amdgcn_s_barrier();

  #pragma unroll 1
  for (int T = 0; T < NT; ++T) {
    const int s = T & 1;
    const unsigned short* A0 = &As[s][0];
    const unsigned short* B0 = &Bs[s][0];
    short8 af[4][2], bfr[4][2];

    // ---- phase 0: read A-ih0 (8) + B-jh0 (4) ; stage A-ih1(T+1) ----
    #pragma unroll
    for (int i = 0; i < 4; ++i) {
      const unsigned short* ap = A0 + aRow0 + i * 16 * BK;
      af[i][0] = *(const short8*)(ap + swz0);
      af[i][1] = *(const short8*)(ap + swz1);
    }
    #pragma unroll
    for (int j = 0; j < 2; ++j) {
      const unsigned short* bp = B0 + bRow0 + j * 16 * BK;
      bfr[j][0] = *(const short8*)(bp + swz0);
      bfr[j][1] = *(const short8*)(bp + swz1);
    }
    if (T + 1 < NT) STAGE_A(1, (T + 1) & 1, T + 1);
    __builtin_amdgcn_s_barrier();
    asm volatile("s_waitcnt lgkmcnt(0)" ::: "memory");
    __builtin_amdgcn_sched_barrier(0);
    __builtin_amdgcn_s_setprio(1);
    #pragma unroll
    for (int i = 0; i < 4; ++i)
      #pragma unroll
      for (int j = 0; j < 2; ++j) {
        acc[i][j] = __builtin_amdgcn_mfma_f32_16x16x32_bf16(af[i][0], bfr[j][0], acc[i][j], 0, 0, 0);
        acc[i][j] = __builtin_amdgcn_mfma_f32_16x16x32_bf16(af[i][1], bfr[j][1], acc[i][j], 0, 0, 0);
      }
    __builtin_amdgcn_s_setprio(0);
    __builtin_amdgcn_s_barrier();

    // ---- phase 1: read B-jh1 (4) ; stage A-ih0(T+2) into current slot ----
    #pragma unroll
    for (int j = 2; j < 4; ++j) {
      const unsigned short* bp = B0 + bRow0 + j * 16 * BK;
      bfr[j][0] = *(const short8*)(bp + swz0);
      bfr[j][1] = *(const short8*)(bp + swz1);
    }
    if (T + 2 < NT) STAGE_A(0, s, T + 2);
    __builtin_amdgcn_s_barrier();
    asm volatile("s_waitcnt lgkmcnt(0)" ::: "memory");
    __builtin_amdgcn_sched_barrier(0);
    __builtin_amdgcn_s_setprio(1);
    #pragma unroll
    for (int i = 0; i < 4; ++i)
      #pragma unroll
      for (int j = 2; j < 4; ++j) {
        acc[i][j] = __builtin_amdgcn_mfma_f32_16x16x32_bf16(af[i][0], bfr[j][0], acc[i][j], 0, 0, 0);
        acc[i][j] = __builtin_amdgcn_mfma_f32_16x16x32_bf16(af[i][1], bfr[j][1], acc[i][j], 0, 0, 0);
      }
    __builtin_amdgcn_s_setprio(0);
    __builtin_amdgcn_s_barrier();

    // ---- phase 2: read A-ih1 (8, reuse af regs) ; stage B-jh0(T+2) ----
    #pragma unroll
    for (int i = 0; i < 4; ++i) {
      const unsigned short* ap = A0 + aRow0 + (4 + i) * 16 * BK;
      af[i][0] = *(const short8*)(ap + swz0);
      af[i][1] = *(const short8*)(ap + swz1);
    }
    if (T + 2 < NT) STAGE_B(0, s, T + 2);
    __builtin_amdgcn_s_barrier();
    asm volatile("s_waitcnt lgkmcnt(0)" ::: "memory");
    __builtin_amdgcn_sched_barrier(0);
    __builtin_amdgcn_s_setprio(1);
    #pragma unroll
    for (int i = 0; i < 4; ++i)
      #pragma unroll
      for (int j = 0; j < 2; ++j) {
        acc[4 + i][j] = __builtin_amdgcn_mfma_f32_16x16x32_bf16(af[i][0], bfr[j][0], acc[4 + i][j], 0, 0, 0);
        acc[4 + i][j] = __builtin_amdgcn_mfma_f32_16x16x32_bf16(af[i][1], bfr[j][1], acc[4 + i][j], 0, 0, 0);
      }
    __builtin_amdgcn_s_setprio(0);
    __builtin_amdgcn_s_barrier();

    // ---- phase 3: no reads ; stage B-jh1(T+2) ; MFMA ; vmcnt ; barrier ----
    if (T + 2 < NT) STAGE_B(1, s, T + 2);
    __builtin_amdgcn_s_barrier();
    __builtin_amdgcn_s_setprio(1);
    #pragma unroll
    for (int i = 0; i < 4; ++i)
      #pragma unroll
      for (int j = 2; j < 4; ++j) {
        acc[4 + i][j] = __builtin_amdgcn_mfma_f32_16x16x32_bf16(af[i][0], bfr[j][0], acc[4 + i][j], 0, 0, 0);
        acc[4 + i][j] = __builtin_amdgcn_mfma_f32_16x16x32_bf16(af[i][1], bfr[j][1], acc[4 + i][j], 0, 0, 0);
      }
    __builtin_amdgcn_s_setprio(0);
    if (T < NT - 1) {
      if (T + 1 == NT - 1) { asm volatile("s_waitcnt vmcnt(0)" ::: "memory"); }
      else                 { asm volatile("s_waitcnt vmcnt(6)" ::: "memory"); }
    }
    __builtin_amdgcn_s_barrier();
  }
#undef STAGE_A
#undef STAGE_B

  // epilogue: d^2 = ||x||^2 + ||y||^2 - 2*dot ; C/D layout col=lane&15, row=quad*4+reg
  float lmin = 3.4e38f;
  #pragma unroll
  for (int i = 0; i < 8; ++i) {
    const int mbase = rowA0 + wr * 128 + i * 16 + quad * 4;
    float4 nxv = *(const float4*)(nx + mbase);
    #pragma unroll
    for (int j = 0; j < 4; ++j) {
      const int n = rowB0 + wc * 64 + j * 16 + m;
      const float nyv = ny[n];
      f32x4 a = acc[i][j];
      lmin = fminf(lmin, nxv.x + nyv - 2.0f * a[0]);
      lmin = fminf(lmin, nxv.y + nyv - 2.0f * a[1]);
      lmin = fminf(lmin, nxv.z + nyv - 2.0f * a[2]);
      lmin = fminf(lmin, nxv.w + nyv - 2.0f * a[3]);
    }
  }
  #pragma unroll
  for (int off = 32; off; off >>= 1) lmin = fminf(lmin, __shfl_down(lmin, off, 64));
  if (lane == 0) wmin[wave] = lmin;
  __syncthreads();
  if (tid == 0) {
    float mn = wmin[0];
    #pragma unroll
    for (int w = 1; w < 8; ++w) mn = fminf(mn, wmin[w]);
    atomicMin(minp, __float_as_uint(fmaxf(mn, 0.0f)));
  }
}

// ---- fallback (only if ws too small): exact fp32 brute force ----
__global__ __launch_bounds__(64) void k_initmin(unsigned int* minp) {
  if (threadIdx.x == 0) *minp = 0x7f800000u;
}

__global__ __launch_bounds__(256) void k_brute(
    const float* __restrict__ pred, const float* __restrict__ cand,
    unsigned int* __restrict__ minp)
{
  __shared__ float yrow[DD];
  __shared__ float wm[4];
  const int c = blockIdx.x;
  for (int i = threadIdx.x; i < DD; i += 256) yrow[i] = cand[(size_t)c * DD + i];
  __syncthreads();
  float lmin = 3.4e38f;
  for (int p = threadIdx.x; p < P; p += 256) {
    const float* xp = pred + (size_t)p * DD;
    float s = 0.f;
    for (int k = 0; k < DD; ++k) { float d = xp[k] - yrow[k]; s = fmaf(d, d, s); }
    lmin = fminf(lmin, s);
  }
  #pragma unroll
  for (int off = 32; off; off >>= 1) lmin = fminf(lmin, __shfl_down(lmin, off, 64));
  if ((threadIdx.x & 63) == 0) wm[threadIdx.x >> 6] = lmin;
  __syncthreads();
  if (threadIdx.x == 0) {
    float mn = fminf(fminf(wm[0], wm[1]), fminf(wm[2], wm[3]));
    atomicMin(minp, __float_as_uint(fmaxf(mn, 0.0f)));
  }
}

__global__ __launch_bounds__(64) void k_finalize(const unsigned int* minp, float* out) {
  if (threadIdx.x == 0) out[0] = sqrtf(__uint_as_float(*minp));
}

extern "C" void kernel_launch(void* const* d_in, const int* in_sizes, int n_in,
                              void* d_out, int out_size, void* d_ws, size_t ws_size,
                              hipStream_t stream) {
  const float* pred = (const float*)d_in[0];
  const float* cand = (const float*)d_in[1];
  float* out = (float*)d_out;

  // ws layout: [0] min-bits | +16 floats: nx[2048] | ny[65536] | Abf bf16[2048*512] | Bbf bf16[65536*512]
  unsigned int* minp = (unsigned int*)d_ws;
  float* wsf = (float*)d_ws;
  float* nx = wsf + 16;
  float* ny = nx + P;
  unsigned short* Abf = (unsigned short*)(ny + R);
  unsigned short* Bbf = Abf + (size_t)P * DD;
  const size_t need = (size_t)(16 + P + R) * 4 + ((size_t)P * DD + (size_t)R * DD) * 2;

  if (ws_size >= need) {
    const int rows = P + R;                 // 67584 rows, 4 waves/block
    k_convert<<<rows / 4, 256, 0, stream>>>(pred, cand, Abf, Bbf, nx, ny, minp);
    k_gemm_min<<<(P / BM) * (R / BN), 512, 0, stream>>>(Abf, Bbf, nx, ny, minp);
  } else {
    k_initmin<<<1, 64, 0, stream>>>(minp);
    k_brute<<<R, 256, 0, stream>>>(pred, cand, minp);
  }
  k_finalize<<<1, 64, 0, stream>>>(minp, out);
}